// Round 4
// baseline (624.023 us; speedup 1.0000x reference)
//
#include <hip/hip_runtime.h>
#include <math.h>

// Problem constants (from reference)
#define NN 10000
#define OF  64
#define MAXDEG 64   // P(Poisson(16.4) >= 64) ~ 7e-18/node: ELL-64 is statistically exact

// Persistent mono-kernel: 1024 blocks x 256 thr = exactly 4 blocks/CU on 256 CUs.
// Residency guaranteed: LDS 32 KB (160/32 = 5 blocks/CU), __launch_bounds__(256,4)
// caps VGPR at 128 (4 waves/EU). All blocks resident -> spin barriers cannot
// deadlock. NOT cooperative launch (R6 ban) — plain atomic + agent-scope fence.
#define NBLK 1024
#define GEMM_B 316
#define P0_X  2500
#define P0_W1 2756
#define P0_W2 2788
#define P0_Z  2828

typedef __attribute__((ext_vector_type(8))) short bf16x8_t;   // 8 bf16 = 4 VGPRs
typedef __attribute__((ext_vector_type(4))) float f32x4_t;    // 4 fp32 acc

__device__ inline ushort f2bf(float f) {
    unsigned u = __float_as_uint(f);
    u = (u + 0x7FFF + ((u >> 16) & 1)) >> 16;   // RNE
    return (ushort)u;
}
__device__ inline float bf2f(ushort u) {
    return __uint_as_float(((unsigned)u) << 16);
}

// global -> LDS direct DMA, 16 B/lane. LDS dest = wave-uniform base + lane*16.
#define GLL(gp, lp) __builtin_amdgcn_global_load_lds(                         \
    (const __attribute__((address_space(1))) unsigned int*)(gp),              \
    (__attribute__((address_space(3))) unsigned int*)(lp), 16, 0, 0)

// Grid-wide barrier for a fully-resident grid. Release: __threadfence() (agent
// fence -> L2 writeback) before arrive; acquire: agent-scope atomic load + fence
// after. Cross-XCD correctness per guide §6 G16 (device-scope atomics/fences).
__device__ inline void gbar(int* cnt, int* flag) {
    __syncthreads();
    if (threadIdx.x == 0) {
        __threadfence();
        if (atomicAdd(cnt, 1) == NBLK - 1) {
            __hip_atomic_store(flag, 1, __ATOMIC_RELEASE, __HIP_MEMORY_SCOPE_AGENT);
        } else {
            while (__hip_atomic_load(flag, __ATOMIC_ACQUIRE,
                                     __HIP_MEMORY_SCOPE_AGENT) == 0)
                __builtin_amdgcn_s_sleep(2);
        }
        __threadfence();
    }
    __syncthreads();
}

__global__ __launch_bounds__(256, 4) void k_mono(
        const float* __restrict__ X,   ushort* __restrict__ Xb,
        const float* __restrict__ W1,  ushort* __restrict__ W1T,
        const float* __restrict__ W2,  ushort* __restrict__ W2T,
        const int* __restrict__ src,   const int* __restrict__ dst,
        int* __restrict__ gdeg,        int* __restrict__ ell,
        float* __restrict__ wts,
        ushort* __restrict__ h1b,      ushort* __restrict__ h2b,
        const float* __restrict__ b1,  const float* __restrict__ b2,
        float* __restrict__ out,       int E, int* __restrict__ bar) {
    __shared__ __align__(16) char smem[32768];
    int tid = threadIdx.x;

    // ================= P0: conversions + transposes + gdeg zero =================
    {
        float (*tl)[33] = (float(*)[33])smem;
        for (int u = blockIdx.x; u < P0_Z; u += NBLK) {
            if (u < P0_X) {
                int i = (u * 256 + tid) * 2;
                const float4* Xv = (const float4*)X;
                float4 v0 = Xv[i], v1 = Xv[i + 1];
                ushort4 o0, o1;
                o0.x = f2bf(v0.x); o0.y = f2bf(v0.y); o0.z = f2bf(v0.z); o0.w = f2bf(v0.w);
                o1.x = f2bf(v1.x); o1.y = f2bf(v1.y); o1.z = f2bf(v1.z); o1.w = f2bf(v1.w);
                ((ushort4*)Xb)[i] = o0;
                ((ushort4*)Xb)[i + 1] = o1;
            } else if (u < P0_W2) {
                // each block hits at most ONE transpose unit (range width 288 < NBLK)
                const float* W; ushort* WT; int N, tile;
                if (u < P0_W1) { W = W1; WT = W1T; N = 512; tile = u - P0_X; }
                else           { W = W2; WT = W2T; N = 64;  tile = u - P0_W1; }
                int k0 = (tile & 15) * 32;
                int n0 = (tile >> 4) * 32;
                int tx = tid & 31, ty = tid >> 5;
#pragma unroll
                for (int i = 0; i < 4; i++)
                    tl[ty + i * 8][tx] = W[(size_t)(k0 + ty + i * 8) * N + n0 + tx];
                __syncthreads();
#pragma unroll
                for (int i = 0; i < 4; i++)
                    WT[(size_t)(n0 + ty + i * 8) * 512 + k0 + tx] = f2bf(tl[tx][ty + i * 8]);
            } else {
                int i = (u - P0_W2) * 256 + tid;
                if (i < NN) gdeg[i] = 0;
            }
        }
    }
    gbar(&bar[0], &bar[1]);

    // ================= P1: GEMM1 (128x128, BK=64) + ELL fill =====================
    // BK=64 (32 KB LDS) keeps the persistent grid at 4 blocks/CU. K-order (kb asc,
    // kc asc) identical to the BK=128 version -> h1b bit-identical.
    {
        ushort* As = (ushort*)smem;              // [128][64]
        ushort* Bs = (ushort*)(smem + 16384);    // [128][64]
        int fillU = (E + 255) / 256;             // 640
        for (int u = blockIdx.x; u < GEMM_B + fillU; u += NBLK) {
            if (u >= GEMM_B) {
                int e = (u - GEMM_B) * 256 + tid;
                if (e < E) {
                    int s = src[e], d = dst[e];
                    int r = atomicAdd(&gdeg[d], 1);
                    if (r < MAXDEG) ell[d * MAXDEG + r] = s;
                }
                continue;
            }
            int lane = tid & 63;
            int wave = tid >> 6;
            int m = lane & 15;
            int q = lane >> 4;
            int wr = wave >> 1;
            int wc = wave & 1;
            int row0 = (u % 79) * 128;
            int col0 = (u / 79) * 128;
            // staging: 1 issue = 1 KB = 8 rows x 128 B. lrow=lane>>3, group p=lane&7.
            // LDS slot p holds global k-group p^lrow; reader row R wants kg at slot kg^(R&7).
            int lrow = lane >> 3;
            int p = lane & 7;
            int koff = (p ^ lrow) * 8;

            f32x4_t acc[4][4];
#pragma unroll
            for (int r = 0; r < 4; r++)
#pragma unroll
                for (int c = 0; c < 4; c++) acc[r][c] = (f32x4_t){0.f, 0.f, 0.f, 0.f};

            for (int kb = 0; kb < 512; kb += 64) {
#pragma unroll
                for (int j = 0; j < 4; j++) {
                    int rloc = wave * 32 + j * 8;
                    GLL(Xb + (size_t)(row0 + rloc + lrow) * 512 + kb + koff,
                        As + rloc * 64);
                    GLL(W1T + (size_t)(col0 + rloc + lrow) * 512 + kb + koff,
                        Bs + rloc * 64);
                }
                __syncthreads();
#pragma unroll
                for (int kc = 0; kc < 2; kc++) {
                    bf16x8_t a[4], bb[4];
                    int slot = ((kc * 4 + q) ^ (m & 7)) * 8;
#pragma unroll
                    for (int r = 0; r < 4; r++)
                        a[r] = *(const bf16x8_t*)(As + (wr * 64 + r * 16 + m) * 64 + slot);
#pragma unroll
                    for (int c = 0; c < 4; c++)
                        bb[c] = *(const bf16x8_t*)(Bs + (wc * 64 + c * 16 + m) * 64 + slot);
#pragma unroll
                    for (int r = 0; r < 4; r++)
#pragma unroll
                        for (int c = 0; c < 4; c++)
                            acc[r][c] = __builtin_amdgcn_mfma_f32_16x16x32_bf16(a[r], bb[c], acc[r][c], 0, 0, 0);
                }
                __syncthreads();
            }
#pragma unroll
            for (int r = 0; r < 4; r++)
#pragma unroll
                for (int c = 0; c < 4; c++)
#pragma unroll
                    for (int reg = 0; reg < 4; reg++) {
                        int row = row0 + wr * 64 + r * 16 + q * 4 + reg;
                        int col = col0 + wc * 64 + c * 16 + m;
                        if (row < NN) h1b[(size_t)row * 512 + col] = f2bf(acc[r][c][reg]);
                    }
        }
    }
    gbar(&bar[2], &bar[3]);

    // ================= P2: agg1 (+b1, relu) + GEMM2 (r @ W2) =====================
    // 4 waves = 4 nodes per visit. Phase A: R15's 16 B/lane ELL gather, wave-
    // private sidx/swt (no barrier). Phase B: all 4 waves MFMA one 16-col tile
    // each; A-frags from XOR-swizzled rlds (rows 4-15 don't-care), B-frags
    // straight from W2T global (L2-resident). K-order matches old gemm64.
    {
        ushort* rlds = (ushort*)smem;            // [16][512] (rows 4+ unwritten)
        int*   sidx  = (int*)(smem + 16384);     // [4][64]
        float* swt   = (float*)(smem + 17408);   // [4][64]
        int w = tid >> 6;
        int t = tid & 63;
        for (int vb = blockIdx.x; vb < NN / 4; vb += NBLK) {
            int v = vb * 4 + w;
            int deg = gdeg[v]; if (deg > MAXDEG) deg = MAXDEG;
            float dv = rsqrtf((float)(deg + 1));
            int s = 0; float wt = 0.f;
            if (t < deg) {                   // slots >= deg are poison; only t<deg reads
                s = ell[v * MAXDEG + t];
                wt = rsqrtf((float)(gdeg[s] + 1)) * dv;
            }
            sidx[w * 64 + t] = s; swt[w * 64 + t] = wt;   // wave-private slice
            wts[v * MAXDEG + t] = wt;        // persist for P3 (0 for t>=deg)

            int fb = t * 8;                  // 8 feats/lane, 16 B
            float acc[8];
            {   // self-loop
                bf16x8_t su = *(const bf16x8_t*)(h1b + (size_t)v * 512 + fb);
                float dv2 = dv * dv;
#pragma unroll
                for (int f = 0; f < 8; f++) acc[f] = bf2f((ushort)su[f]) * dv2;
            }
            int nr = (deg + 3) & ~3;         // extras have w=0, idx=0 (safe address)
            for (int i = 0; i < nr; i += 4) {
                bf16x8_t nb[4]; float wK[4];
#pragma unroll
                for (int k = 0; k < 4; k++) {
                    int sK = sidx[w * 64 + i + k];   // broadcast LDS read
                    wK[k] = swt[w * 64 + i + k];
                    nb[k] = *(const bf16x8_t*)(h1b + (size_t)sK * 512 + fb);
                }
#pragma unroll
                for (int k = 0; k < 4; k++)
#pragma unroll
                    for (int f = 0; f < 8; f++)
                        acc[f] += bf2f((ushort)nb[k][f]) * wK[k];
            }
            bf16x8_t o;
#pragma unroll
            for (int f = 0; f < 8; f++) {
                float xr = acc[f] + b1[fb + f];
                o[f] = (short)f2bf(xr > 0.f ? xr : 0.f);
            }
            // r row w, k-group g=t at XOR-swizzled slot (g&48)|((g&15)^w); reader
            // (row m, group kg) uses (kg&48)|((kg&15)^m): consistent for m==w.
            int slot = (t & 48) | ((t & 15) ^ w);
            *(bf16x8_t*)(rlds + w * 512 + slot * 8) = o;
            __syncthreads();                 // 4 r-rows visible to all waves

            // phase B: wave w computes cols w*16..w*16+15 for the 4 nodes
            int m = t & 15;
            int q = t >> 4;
            f32x4_t qa = (f32x4_t){0.f, 0.f, 0.f, 0.f};
            const ushort* wrow = W2T + (size_t)(w * 16 + m) * 512;
#pragma unroll
            for (int ks = 0; ks < 16; ks++) {
                int kg = ks * 4 + q;
                int sl = (kg & 48) | ((kg & 15) ^ m);
                bf16x8_t af  = *(const bf16x8_t*)(rlds + m * 512 + sl * 8);
                bf16x8_t bfr = *(const bf16x8_t*)(wrow + ks * 32 + q * 8);
                qa = __builtin_amdgcn_mfma_f32_16x16x32_bf16(af, bfr, qa, 0, 0, 0);
            }
#pragma unroll
            for (int reg = 0; reg < 4; reg++) {
                int rl = q * 4 + reg;        // C row; rows 4-15 are don't-care
                if (rl < 4)
                    h2b[(size_t)(vb * 4 + rl) * 64 + w * 16 + m] = f2bf(qa[reg]);
            }
            __syncthreads();                 // before next visit overwrites rlds
        }
    }
    gbar(&bar[4], &bar[5]);

    // ================= P3: agg2 + b2 + log_softmax ===============================
    {
        int*   s3 = (int*)smem;              // [4][64]
        float* w3 = (float*)(smem + 1024);   // [4][64]
        int wv = tid >> 6;
        int t  = tid & 63;
        for (int vb = blockIdx.x; vb < NN / 4; vb += NBLK) {
            int v = vb * 4 + wv;
            int deg = gdeg[v]; if (deg > MAXDEG) deg = MAXDEG;
            float dv = rsqrtf((float)(deg + 1));
            int   e_ = ell[v * MAXDEG + t];
            float w_ = wts[v * MAXDEG + t];
            s3[wv * 64 + t] = (t < deg) ? e_ : 0;   // clamp: poison never dereferenced
            w3[wv * 64 + t] = (t < deg) ? w_ : 0.f;
            // no __syncthreads: wave-local LDS slice

            float acc[8];
#pragma unroll
            for (int k = 0; k < 8; k++) acc[k] = 0.f;
            acc[0] = bf2f(h2b[(size_t)v * 64 + t]) * (dv * dv);

            int nr = (deg + 7) & ~7;
            for (int i = 0; i < nr; i += 8) {
                int   sK[8]; float wK[8];
#pragma unroll
                for (int k = 0; k < 8; k++) { sK[k] = s3[wv * 64 + i + k]; wK[k] = w3[wv * 64 + i + k]; }
#pragma unroll
                for (int k = 0; k < 8; k++)
                    acc[k] += bf2f(h2b[(size_t)sK[k] * 64 + t]) * wK[k];
            }
            float h = ((acc[0] + acc[1]) + (acc[2] + acc[3])) +
                      ((acc[4] + acc[5]) + (acc[6] + acc[7]));
            h += b2[t];
            out[(size_t)v * 64 + t] = h;
            float mx = h;
#pragma unroll
            for (int off = 32; off >= 1; off >>= 1) mx = fmaxf(mx, __shfl_xor(mx, off, 64));
            float e = expf(h - mx);
            float ssum = e;
#pragma unroll
            for (int off = 32; off >= 1; off >>= 1) ssum += __shfl_xor(ssum, off, 64);
            out[(size_t)NN * OF + (size_t)v * 64 + t] = h - mx - logf(ssum);
        }
    }
}

// ---------------- launch ----------------

extern "C" void kernel_launch(void* const* d_in, const int* in_sizes, int n_in,
                              void* d_out, int out_size, void* d_ws, size_t ws_size,
                              hipStream_t stream) {
    const float* x  = (const float*)d_in[0];
    const int*   ei = (const int*)d_in[1];
    const float* W1 = (const float*)d_in[2];
    const float* b1 = (const float*)d_in[3];
    const float* W2 = (const float*)d_in[4];
    const float* b2 = (const float*)d_in[5];
    float* out = (float*)d_out;

    int E = in_sizes[1] / 2;             // 163840
    const int* src = ei;
    const int* dst = ei + E;

    char* w = (char*)d_ws;
    auto carve = [&](size_t bytes) {
        char* p = w;
        w += (bytes + 255) & ~size_t(255);
        return p;
    };
    ushort* Xb     = (ushort*)carve((size_t)NN * 512 * 2);
    ushort* h1b    = (ushort*)carve((size_t)NN * 512 * 2);
    ushort* h2b    = (ushort*)carve((size_t)NN * 64 * 2);
    ushort* W1Tb   = (ushort*)carve((size_t)512 * 512 * 2);
    ushort* W2Tb   = (ushort*)carve((size_t)64 * 512 * 2);
    int*   gdeg    = (int*)carve((size_t)NN * 4);
    int*   ell     = (int*)carve((size_t)NN * MAXDEG * 4);   // 2.56 MB
    float* wts     = (float*)carve((size_t)NN * MAXDEG * 4); // 2.56 MB
    int*   bar     = (int*)carve(256);
    (void)ws_size;

    // R17: single persistent dispatch. Barrier slots must be zero each iteration
    // (workspace is re-poisoned between iterations); memset is graph-capturable.
    hipMemsetAsync(bar, 0, 256, stream);
    k_mono<<<NBLK, 256, 0, stream>>>(x, Xb, W1, W1Tb, W2, W2Tb, src, dst,
                                     gdeg, ell, wts, h1b, h2b, b1, b2, out,
                                     E, bar);
}

// Round 5
// 131.389 us; speedup vs baseline: 4.7494x; 4.7494x over previous
//
#include <hip/hip_runtime.h>
#include <math.h>

// Problem constants (from reference)
#define NN 10000
#define INF 512
#define HF  512
#define OF  64
#define NE  163840
#define MAXDEG 64   // P(Poisson(16.4) >= 64) ~ 7e-18/node: ELL-64 is statistically exact

typedef __attribute__((ext_vector_type(8))) short bf16x8_t;   // 8 bf16 = 4 VGPRs
typedef __attribute__((ext_vector_type(4))) float f32x4_t;    // 4 fp32 acc

__device__ inline ushort f2bf(float f) {
    unsigned u = __float_as_uint(f);
    u = (u + 0x7FFF + ((u >> 16) & 1)) >> 16;   // RNE
    return (ushort)u;
}
__device__ inline float bf2f(ushort u) {
    return __uint_as_float(((unsigned)u) << 16);
}

// global -> LDS direct DMA, 16 B/lane. LDS dest = wave-uniform base + lane*16.
#define GLL(gp, lp) __builtin_amdgcn_global_load_lds(                         \
    (const __attribute__((address_space(1))) unsigned int*)(gp),              \
    (__attribute__((address_space(3))) unsigned int*)(lp), 16, 0, 0)

// R17 lesson (mono-kernel, 569 us): __launch_bounds__(256,4) caps VGPR at 64 and
// strangles the GEMM; persistent-grid phase barriers are NOT worth it here.
// Fixed harness overhead is ~55 us/iteration regardless of kernel structure —
// optimize the ~75 us of actual kernel time only.

// ---------------- D1: conversions + gdeg zero (grid-partitioned) ----------------
#define CCB_X  2500
#define CCB_W1 2756
#define CCB_W2 2788
#define CCB_Z  2828
__global__ __launch_bounds__(256) void k_cvt(const float* __restrict__ X,
                                             ushort* __restrict__ Xb,
                                             const float* __restrict__ W1,
                                             ushort* __restrict__ W1T,
                                             const float* __restrict__ W2,
                                             ushort* __restrict__ W2T,
                                             int* __restrict__ gdeg) {
    __shared__ float tl[32][33];
    int b = blockIdx.x, t = threadIdx.x;
    if (b < CCB_X) {
        int i = (b * 256 + t) * 2;
        const float4* Xv = (const float4*)X;
        float4 v0 = Xv[i], v1 = Xv[i + 1];
        ushort4 o0, o1;
        o0.x = f2bf(v0.x); o0.y = f2bf(v0.y); o0.z = f2bf(v0.z); o0.w = f2bf(v0.w);
        o1.x = f2bf(v1.x); o1.y = f2bf(v1.y); o1.z = f2bf(v1.z); o1.w = f2bf(v1.w);
        ((ushort4*)Xb)[i] = o0;
        ((ushort4*)Xb)[i + 1] = o1;
    } else if (b < CCB_W2) {
        const float* W; ushort* WT; int N, tile;
        if (b < CCB_W1) { W = W1; WT = W1T; N = 512; tile = b - CCB_X; }
        else            { W = W2; WT = W2T; N = 64;  tile = b - CCB_W1; }
        int k0 = (tile & 15) * 32;
        int n0 = (tile >> 4) * 32;
        int tx = t & 31, ty = t >> 5;
#pragma unroll
        for (int i = 0; i < 4; i++)
            tl[ty + i * 8][tx] = W[(size_t)(k0 + ty + i * 8) * N + n0 + tx];
        __syncthreads();
#pragma unroll
        for (int i = 0; i < 4; i++)
            WT[(size_t)(n0 + ty + i * 8) * 512 + k0 + tx] = f2bf(tl[tx][ty + i * 8]);
    } else {
        int i = (b - CCB_W2) * 256 + t;
        if (i < NN) gdeg[i] = 0;
    }
}

// ---------------- D2: MFMA GEMM1 (64x128 tile, BK=128, GLL + XOR swizzle) + ELL --
// R18: was 128x128 = 316 blocks = 1.23 blocks/CU — no co-resident block to hide
// the vmcnt(0) barrier drain (m114: cross-block wave overlap is what hides it).
// Now 64x128 = 157x4 = 628 blocks; LDS 48 KB -> 3 blocks/CU, ~2.45 available/CU.
// K-order (kb asc, kc asc) and fragment data unchanged -> h1b bit-identical.
// LDS row = 128 k = 16 groups x 16B; slot = g ^ (row&15); bank sets stay balanced.
#define GEMM_RP 157
#define GEMM_B  (GEMM_RP * 4)
__global__ __launch_bounds__(256) void k_gemm_ell(const ushort* __restrict__ Xb,
                                                  const ushort* __restrict__ WT,
                                                  ushort* __restrict__ Y,
                                                  const int* __restrict__ src,
                                                  const int* __restrict__ dst,
                                                  int* __restrict__ gdeg,
                                                  int* __restrict__ ell, int E) {
    __shared__ ushort As[64 * 128];    // 16 KB
    __shared__ ushort Bs[128 * 128];   // 32 KB
    int b = blockIdx.x;
    int tid = threadIdx.x;
    if (b >= GEMM_B) {
        int e = (b - GEMM_B) * 256 + tid;
        if (e < E) {
            int s = src[e], d = dst[e];
            int r = atomicAdd(&gdeg[d], 1);
            if (r < MAXDEG) ell[d * MAXDEG + r] = s;
        }
        return;
    }
    int lane = tid & 63;
    int wave = tid >> 6;
    int m = lane & 15;
    int q = lane >> 4;
    int row0 = (b % GEMM_RP) * 64;     // 157*64 = 10048: rows 10000+ staged from
    int col0 = (b / GEMM_RP) * 128;    // adjacent workspace (safe), never stored

    // staging lane map: 1 issue = 1 KB = 4 rows x 256 B; lrow = lane>>4, chunk p = lane&15.
    // LDS slot s = p; global k-group g = p ^ (row&15); row&15 = (j*4+lrow)&15 -> 4 patterns.
    int lrow = lane >> 4;
    int p = lane & 15;
    int koff[4];
#pragma unroll
    for (int jm = 0; jm < 4; jm++) koff[jm] = (p ^ ((jm * 4 + lrow) & 15)) * 8;

    f32x4_t acc[4][2];
#pragma unroll
    for (int r = 0; r < 4; r++)
#pragma unroll
        for (int c = 0; c < 2; c++) acc[r][c] = (f32x4_t){0.f, 0.f, 0.f, 0.f};

    for (int kb = 0; kb < 512; kb += 128) {
        // A: 64 rows = 4 issues/wave; B: 128 rows = 8 issues/wave
#pragma unroll
        for (int j = 0; j < 4; j++) {
            int rloc = wave * 16 + j * 4;   // wave*16 mult of 16: (rloc+lrow)&15 = (j*4+lrow)&15
            GLL(Xb + (size_t)(row0 + rloc + lrow) * 512 + kb + koff[j & 3],
                As + rloc * 128);
        }
#pragma unroll
        for (int j = 0; j < 8; j++) {
            int rloc = wave * 32 + j * 4;   // wave*32 mult of 16: same koff pattern
            GLL(WT + (size_t)(col0 + rloc + lrow) * 512 + kb + koff[j & 3],
                Bs + rloc * 128);
        }
        __syncthreads();
#pragma unroll
        for (int kc = 0; kc < 4; kc++) {
            bf16x8_t a[4], bb[2];
            int slot = ((kc * 4 + q) ^ m) * 8;
#pragma unroll
            for (int r = 0; r < 4; r++)
                a[r] = *(const bf16x8_t*)(As + (r * 16 + m) * 128 + slot);
#pragma unroll
            for (int c = 0; c < 2; c++)
                bb[c] = *(const bf16x8_t*)(Bs + (wave * 32 + c * 16 + m) * 128 + slot);
#pragma unroll
            for (int r = 0; r < 4; r++)
#pragma unroll
                for (int c = 0; c < 2; c++)
                    acc[r][c] = __builtin_amdgcn_mfma_f32_16x16x32_bf16(a[r], bb[c], acc[r][c], 0, 0, 0);
        }
        __syncthreads();
    }
#pragma unroll
    for (int r = 0; r < 4; r++) {
#pragma unroll
        for (int c = 0; c < 2; c++) {
#pragma unroll
            for (int reg = 0; reg < 4; reg++) {
                int row = row0 + r * 16 + q * 4 + reg;
                int col = col0 + wave * 32 + c * 16 + m;
                if (row < NN) Y[(size_t)row * 512 + col] = f2bf(acc[r][c][reg]);
            }
        }
    }
}

// ---------------- FUSED: aggregate layer 1 + GEMM2 (r @ W2) ---------------------
// R16 structure (proven ~tie with split version, one less dispatch + no a1b
// round-trip). Block = 8 waves = 8 nodes. Phase A (all 8 waves): 16 B/lane ELL
// gather -> r row (bf16) into wave-private XOR-swizzled LDS row. One barrier.
// Phase B (waves 0-3): MFMA q[16x64] = r @ W2, A-frags from LDS, B-frags loaded
// DIRECTLY from W2T global (L2-resident, 16 B/lane). MFMA rows 8-15 are garbage
// from unwritten LDS rows — C rows depend only on A rows, so they aren't stored.
// K-order (ks asc, 32/step) matches the old gemm64 -> h2b bit-identical.
__global__ __launch_bounds__(512) void k_agg1_gemm2(const ushort* __restrict__ h1b,
                                                    const int* __restrict__ gdeg,
                                                    const int* __restrict__ ell,
                                                    const float* __restrict__ b1,
                                                    const ushort* __restrict__ W2T,
                                                    ushort* __restrict__ h2b,
                                                    float* __restrict__ wts) {
    __shared__ ushort rlds[16 * 512];   // 16 KB; rows 8..15 never written (don't-care)
    __shared__ int   sidx[8][64];
    __shared__ float swt[8][64];
    int w = threadIdx.x >> 6;          // wave -> node slot 0..7
    int t = threadIdx.x & 63;          // lane
    int v = blockIdx.x * 8 + w;        // NN = 8 * 1250: always in-bounds

    // ---- phase A: ELL gather + bias + relu (wave-private, no barrier) ----
    int deg = gdeg[v]; if (deg > MAXDEG) deg = MAXDEG;
    float dv = rsqrtf((float)(deg + 1));
    int s = 0; float wt = 0.f;
    if (t < deg) {
        s = ell[v * MAXDEG + t];       // slots >= deg are poison; only t<deg reads
        wt = rsqrtf((float)(gdeg[s] + 1)) * dv;
    }
    sidx[w][t] = s; swt[w][t] = wt;    // wave-private slice: no barrier needed here
    wts[v * MAXDEG + t] = wt;          // persist for agg2 (0 for t>=deg)

    int fb = t * 8;                    // 8 feats/lane, 16 B
    float acc[8];
    {   // self-loop
        bf16x8_t su = *(const bf16x8_t*)(h1b + (size_t)v * 512 + fb);
        float dv2 = dv * dv;
#pragma unroll
        for (int f = 0; f < 8; f++) acc[f] = bf2f((ushort)su[f]) * dv2;
    }
    int nr = (deg + 3) & ~3;           // extras have w=0, idx=0 (safe address)
    for (int i = 0; i < nr; i += 4) {
        bf16x8_t nb[4]; float wK[4];
#pragma unroll
        for (int k = 0; k < 4; k++) {
            int sK = sidx[w][i + k];   // broadcast LDS read
            wK[k] = swt[w][i + k];
            nb[k] = *(const bf16x8_t*)(h1b + (size_t)sK * 512 + fb);
        }
#pragma unroll
        for (int k = 0; k < 4; k++)
#pragma unroll
            for (int f = 0; f < 8; f++)
                acc[f] += bf2f((ushort)nb[k][f]) * wK[k];
    }
    bf16x8_t o;
#pragma unroll
    for (int f = 0; f < 8; f++) {
        float x = acc[f] + b1[fb + f];
        o[f] = (short)f2bf(x > 0.f ? x : 0.f);
    }
    // write r row w, k-group g = t, at XOR-swizzled slot (g&48) | ((g&15)^w).
    // Reader (row m, group kg) uses (kg&48) | ((kg&15)^m): consistent for m==w,
    // and the ^m spread breaks the 1 KB row-stride bank collision on reads.
    int slot = (t & 48) | ((t & 15) ^ w);
    *(bf16x8_t*)(rlds + w * 512 + slot * 8) = o;
    __syncthreads();                   // all 8 r-rows visible to waves 0-3

    // ---- phase B: q = r @ W2 (waves 0-3, one 16-col tile each) ----
    if (w >= 4) return;                // no further barriers: early exit is safe
    int m = t & 15;
    int q = t >> 4;
    f32x4_t qa = (f32x4_t){0.f, 0.f, 0.f, 0.f};
    const ushort* wrow = W2T + (size_t)(w * 16 + m) * 512;
#pragma unroll
    for (int ks = 0; ks < 16; ks++) {
        int kg = ks * 4 + q;                      // k-group 0..63 (8 bf16 each)
        int sl = (kg & 48) | ((kg & 15) ^ m);     // de-swizzle for row m
        bf16x8_t af  = *(const bf16x8_t*)(rlds + m * 512 + sl * 8);
        bf16x8_t bfr = *(const bf16x8_t*)(wrow + ks * 32 + q * 8);
        qa = __builtin_amdgcn_mfma_f32_16x16x32_bf16(af, bfr, qa, 0, 0, 0);
    }
#pragma unroll
    for (int reg = 0; reg < 4; reg++) {
        int rl = q * 4 + reg;                     // C row; rows 8-15 are don't-care
        if (rl < 8)
            h2b[(size_t)(blockIdx.x * 8 + rl) * 64 + w * 16 + m] = f2bf(qa[reg]);
    }
}

// ---------------- aggregate layer 2 + bias + log_softmax (4 nodes / block) ------
// 4 nodes per 256-thread block, one wave per node with a private LDS slice.
// No barrier: each wave writes and reads only its own slice. 32 waves/CU.
// R13 lesson: ell slots >= deg are uninitialized poison — clamp the INDEX before
// any gather uses it; w=0 does not guard the load address.
__global__ __launch_bounds__(256) void k_agg2_lsm(const ushort* __restrict__ h2b,
                                                  const int* __restrict__ gdeg,
                                                  const int* __restrict__ ell,
                                                  const float* __restrict__ wts,
                                                  const float* __restrict__ b,
                                                  float* __restrict__ out) {
    __shared__ int   sidx[4][64];
    __shared__ float swt[4][64];
    int t = threadIdx.x & 63;
    int w = threadIdx.x >> 6;
    int v = blockIdx.x * 4 + w;            // NN % 4 == 0: always in-bounds
    int deg = gdeg[v]; if (deg > MAXDEG) deg = MAXDEG;
    float dv = rsqrtf((float)(deg + 1));
    int   e_ = ell[v * MAXDEG + t];        // coalesced, in-bounds
    float w_ = wts[v * MAXDEG + t];        // coalesced, 0 for t>=deg
    sidx[w][t] = (t < deg) ? e_ : 0;       // clamp index: poison never dereferenced
    swt[w][t]  = (t < deg) ? w_ : 0.f;
    // no __syncthreads: wave-local LDS slice

    float acc[8];
#pragma unroll
    for (int k = 0; k < 8; k++) acc[k] = 0.f;
    acc[0] = bf2f(h2b[(size_t)v * 64 + t]) * (dv * dv);

    int nr = (deg + 7) & ~7;
    for (int i = 0; i < nr; i += 8) {
        int   sK[8]; float wK[8];
#pragma unroll
        for (int k = 0; k < 8; k++) { sK[k] = sidx[w][i + k]; wK[k] = swt[w][i + k]; }
#pragma unroll
        for (int k = 0; k < 8; k++)
            acc[k] += bf2f(h2b[(size_t)sK[k] * 64 + t]) * wK[k];
    }
    float h = ((acc[0] + acc[1]) + (acc[2] + acc[3])) +
              ((acc[4] + acc[5]) + (acc[6] + acc[7]));
    h += b[t];
    out[(size_t)v * 64 + t] = h;           // output 0: h
    float m = h;
#pragma unroll
    for (int off = 32; off >= 1; off >>= 1) m = fmaxf(m, __shfl_xor(m, off, 64));
    float e = expf(h - m);
    float ssum = e;
#pragma unroll
    for (int off = 32; off >= 1; off >>= 1) ssum += __shfl_xor(ssum, off, 64);
    out[(size_t)NN * OF + (size_t)v * 64 + t] = h - m - logf(ssum);  // output 1
}

// ---------------- launch ----------------

extern "C" void kernel_launch(void* const* d_in, const int* in_sizes, int n_in,
                              void* d_out, int out_size, void* d_ws, size_t ws_size,
                              hipStream_t stream) {
    const float* x  = (const float*)d_in[0];
    const int*   ei = (const int*)d_in[1];
    const float* W1 = (const float*)d_in[2];
    const float* b1 = (const float*)d_in[3];
    const float* W2 = (const float*)d_in[4];
    const float* b2 = (const float*)d_in[5];
    float* out = (float*)d_out;

    int E = in_sizes[1] / 2;             // 163840
    const int* src = ei;
    const int* dst = ei + E;

    char* w = (char*)d_ws;
    auto carve = [&](size_t bytes) {
        char* p = w;
        w += (bytes + 255) & ~size_t(255);
        return p;
    };
    ushort* Xb     = (ushort*)carve((size_t)NN * 512 * 2);
    ushort* h1b    = (ushort*)carve((size_t)NN * 512 * 2);
    ushort* h2b    = (ushort*)carve((size_t)NN * 64 * 2);
    ushort* W1Tb   = (ushort*)carve((size_t)512 * 512 * 2);
    ushort* W2Tb   = (ushort*)carve((size_t)64 * 512 * 2);
    int*   gdeg    = (int*)carve((size_t)NN * 4);
    int*   ell     = (int*)carve((size_t)NN * MAXDEG * 4);   // 2.56 MB
    float* wts     = (float*)carve((size_t)NN * MAXDEG * 4); // 2.56 MB
    (void)ws_size;

    // 4 dispatches. R12 lesson: gather phase keeps full block count / occupancy.
    // R6 lesson: no cooperative launch. R17 lesson: no persistent mono-kernel.
    int fillB = (E + 255) / 256;
    k_cvt<<<CCB_Z, 256, 0, stream>>>(x, Xb, W1, W1Tb, W2, W2Tb, gdeg);
    k_gemm_ell<<<GEMM_B + fillB, 256, 0, stream>>>(Xb, W1Tb, h1b, src, dst,
                                                   gdeg, ell, E);
    k_agg1_gemm2<<<NN / 8, 512, 0, stream>>>(h1b, gdeg, ell, b1, W2Tb, h2b, wts);
    k_agg2_lsm<<<NN / 4, 256, 0, stream>>>(h2b, gdeg, ell, wts, b2, out);
}

// Round 6
// 127.973 us; speedup vs baseline: 4.8762x; 1.0267x over previous
//
#include <hip/hip_runtime.h>
#include <math.h>

// Problem constants (from reference)
#define NN 10000
#define INF 512
#define HF  512
#define OF  64
#define NE  163840
#define MAXDEG 64   // P(Poisson(16.4) >= 64) ~ 7e-18/node: ELL-64 is statistically exact

// R19 (final): revert to the best-measured artifact (126.6/127.2 us across two
// sessions). Session evidence: six structurally distinct variants (agg restructures
// x3, agg1+GEMM2 fusion, GEMM1 retiles x2, persistent mono-kernel) all land in
// 126.6-131.9 us. Measured decomposition: ~45-55 us fixed harness overhead
// (R17: 624 total vs 569 kernel with ONE dispatch; 256 MiB poison fills at
// 43-47 us in the trace) + ~72 us kernel time at composite floor (LLC-bound
// 174 MB ELL gather ~15-20, GEMM1 ~10, streaming ~12, drains ~10). Remaining
// levers are ~3 us each, below the +-3 us bench noise.

typedef __attribute__((ext_vector_type(8))) short bf16x8_t;   // 8 bf16 = 4 VGPRs
typedef __attribute__((ext_vector_type(4))) float f32x4_t;    // 4 fp32 acc

__device__ inline ushort f2bf(float f) {
    unsigned u = __float_as_uint(f);
    u = (u + 0x7FFF + ((u >> 16) & 1)) >> 16;   // RNE
    return (ushort)u;
}
__device__ inline float bf2f(ushort u) {
    return __uint_as_float(((unsigned)u) << 16);
}

// global -> LDS direct DMA, 16 B/lane. LDS dest = wave-uniform base + lane*16.
#define GLL(gp, lp) __builtin_amdgcn_global_load_lds(                         \
    (const __attribute__((address_space(1))) unsigned int*)(gp),              \
    (__attribute__((address_space(3))) unsigned int*)(lp), 16, 0, 0)

// ---------------- D1: conversions + gdeg zero (grid-partitioned) ----------------
#define CCB_X  2500
#define CCB_W1 2756
#define CCB_W2 2788
#define CCB_Z  2828
__global__ __launch_bounds__(256) void k_cvt(const float* __restrict__ X,
                                             ushort* __restrict__ Xb,
                                             const float* __restrict__ W1,
                                             ushort* __restrict__ W1T,
                                             const float* __restrict__ W2,
                                             ushort* __restrict__ W2T,
                                             int* __restrict__ gdeg) {
    __shared__ float tl[32][33];
    int b = blockIdx.x, t = threadIdx.x;
    if (b < CCB_X) {
        int i = (b * 256 + t) * 2;
        const float4* Xv = (const float4*)X;
        float4 v0 = Xv[i], v1 = Xv[i + 1];
        ushort4 o0, o1;
        o0.x = f2bf(v0.x); o0.y = f2bf(v0.y); o0.z = f2bf(v0.z); o0.w = f2bf(v0.w);
        o1.x = f2bf(v1.x); o1.y = f2bf(v1.y); o1.z = f2bf(v1.z); o1.w = f2bf(v1.w);
        ((ushort4*)Xb)[i] = o0;
        ((ushort4*)Xb)[i + 1] = o1;
    } else if (b < CCB_W2) {
        const float* W; ushort* WT; int N, tile;
        if (b < CCB_W1) { W = W1; WT = W1T; N = 512; tile = b - CCB_X; }
        else            { W = W2; WT = W2T; N = 64;  tile = b - CCB_W1; }
        int k0 = (tile & 15) * 32;
        int n0 = (tile >> 4) * 32;
        int tx = t & 31, ty = t >> 5;
#pragma unroll
        for (int i = 0; i < 4; i++)
            tl[ty + i * 8][tx] = W[(size_t)(k0 + ty + i * 8) * N + n0 + tx];
        __syncthreads();
#pragma unroll
        for (int i = 0; i < 4; i++)
            WT[(size_t)(n0 + ty + i * 8) * 512 + k0 + tx] = f2bf(tl[tx][ty + i * 8]);
    } else {
        int i = (b - CCB_W2) * 256 + t;
        if (i < NN) gdeg[i] = 0;
    }
}

// ---------------- D2: MFMA GEMM1 (128x128, BK=128, GLL + XOR swizzle) + ELL --------
// BK=128: 4 barriers instead of 8 — at ~1.2 blocks/CU the vmcnt(0) barrier drain
// is un-hidden, so halving barrier count halves the stall count (m132's BK=128
// regression was an occupancy cliff at 3 blocks/CU; irrelevant here).
// LDS row = 128 k = 16 groups x 16B; slot = g ^ (row&15); bank sets stay balanced.
#define GEMM_B 316
__global__ __launch_bounds__(256) void k_gemm_ell(const ushort* __restrict__ Xb,
                                                  const ushort* __restrict__ WT,
                                                  ushort* __restrict__ Y,
                                                  const int* __restrict__ src,
                                                  const int* __restrict__ dst,
                                                  int* __restrict__ gdeg,
                                                  int* __restrict__ ell, int E) {
    __shared__ ushort As[128 * 128];   // 32 KB
    __shared__ ushort Bs[128 * 128];   // 32 KB
    int b = blockIdx.x;
    int tid = threadIdx.x;
    if (b >= GEMM_B) {
        int e = (b - GEMM_B) * 256 + tid;
        if (e < E) {
            int s = src[e], d = dst[e];
            int r = atomicAdd(&gdeg[d], 1);
            if (r < MAXDEG) ell[d * MAXDEG + r] = s;
        }
        return;
    }
    int lane = tid & 63;
    int wave = tid >> 6;
    int m = lane & 15;
    int q = lane >> 4;
    int wr = wave >> 1;
    int wc = wave & 1;
    int row0 = (b % 79) * 128;
    int col0 = (b / 79) * 128;

    // staging lane map: 1 issue = 1 KB = 4 rows x 256 B; lrow = lane>>4, chunk p = lane&15.
    // LDS slot s = p; global k-group g = p ^ (row&15); row&15 = (j*4+lrow)&15 -> 4 patterns.
    int lrow = lane >> 4;
    int p = lane & 15;
    int koff[4];
#pragma unroll
    for (int jm = 0; jm < 4; jm++) koff[jm] = (p ^ ((jm * 4 + lrow) & 15)) * 8;

    f32x4_t acc[4][4];
#pragma unroll
    for (int r = 0; r < 4; r++)
#pragma unroll
        for (int c = 0; c < 4; c++) acc[r][c] = (f32x4_t){0.f, 0.f, 0.f, 0.f};

    for (int kb = 0; kb < 512; kb += 128) {
#pragma unroll
        for (int j = 0; j < 8; j++) {
            int rloc = wave * 32 + j * 4;
            GLL(Xb + (size_t)(row0 + rloc + lrow) * 512 + kb + koff[j & 3],
                As + rloc * 128);
            GLL(WT + (size_t)(col0 + rloc + lrow) * 512 + kb + koff[j & 3],
                Bs + rloc * 128);
        }
        __syncthreads();
#pragma unroll
        for (int kc = 0; kc < 4; kc++) {
            bf16x8_t a[4], bb[4];
            int slot = ((kc * 4 + q) ^ m) * 8;
#pragma unroll
            for (int r = 0; r < 4; r++)
                a[r] = *(const bf16x8_t*)(As + (wr * 64 + r * 16 + m) * 128 + slot);
#pragma unroll
            for (int c = 0; c < 4; c++)
                bb[c] = *(const bf16x8_t*)(Bs + (wc * 64 + c * 16 + m) * 128 + slot);
#pragma unroll
            for (int r = 0; r < 4; r++)
#pragma unroll
                for (int c = 0; c < 4; c++)
                    acc[r][c] = __builtin_amdgcn_mfma_f32_16x16x32_bf16(a[r], bb[c], acc[r][c], 0, 0, 0);
        }
        __syncthreads();
    }
#pragma unroll
    for (int r = 0; r < 4; r++) {
#pragma unroll
        for (int c = 0; c < 4; c++) {
#pragma unroll
            for (int reg = 0; reg < 4; reg++) {
                int row = row0 + wr * 64 + r * 16 + q * 4 + reg;
                int col = col0 + wc * 64 + c * 16 + m;
                if (row < NN) Y[(size_t)row * 512 + col] = f2bf(acc[r][c][reg]);
            }
        }
    }
}

// ---------------- MFMA GEMM2 (64x64, BK=128, GLL + XOR swizzle) ----------------
__global__ __launch_bounds__(256) void k_gemm64_mfma(const ushort* __restrict__ Ab,
                                                     const ushort* __restrict__ W2T,
                                                     ushort* __restrict__ Y) {
    __shared__ ushort As[64 * 128];    // 16 KB
    __shared__ ushort Bs[64 * 128];    // 16 KB
    int tid = threadIdx.x;
    int lane = tid & 63;
    int wave = tid >> 6;
    int m = lane & 15;
    int q = lane >> 4;
    int row0 = blockIdx.x * 64;

    int lrow = lane >> 4;
    int p = lane & 15;
    int koff[4];
#pragma unroll
    for (int jm = 0; jm < 4; jm++) koff[jm] = (p ^ ((jm * 4 + lrow) & 15)) * 8;

    f32x4_t acc[4];
#pragma unroll
    for (int c = 0; c < 4; c++) acc[c] = (f32x4_t){0.f, 0.f, 0.f, 0.f};

    for (int kb = 0; kb < 512; kb += 128) {
#pragma unroll
        for (int j = 0; j < 4; j++) {
            int rloc = wave * 16 + j * 4;
            GLL(Ab + (size_t)(row0 + rloc + lrow) * 512 + kb + koff[j],
                As + rloc * 128);
            GLL(W2T + (size_t)(rloc + lrow) * 512 + kb + koff[j],
                Bs + rloc * 128);
        }
        __syncthreads();
#pragma unroll
        for (int kc = 0; kc < 4; kc++) {
            int slot = ((kc * 4 + q) ^ m) * 8;
            bf16x8_t a = *(const bf16x8_t*)(As + (wave * 16 + m) * 128 + slot);
#pragma unroll
            for (int c = 0; c < 4; c++) {
                bf16x8_t bfr = *(const bf16x8_t*)(Bs + (c * 16 + m) * 128 + slot);
                acc[c] = __builtin_amdgcn_mfma_f32_16x16x32_bf16(a, bfr, acc[c], 0, 0, 0);
            }
        }
        __syncthreads();
    }
#pragma unroll
    for (int c = 0; c < 4; c++) {
#pragma unroll
        for (int reg = 0; reg < 4; reg++) {
            int row = row0 + wave * 16 + q * 4 + reg;
            int col = c * 16 + m;
            if (row < NN) Y[(size_t)row * 64 + col] = f2bf(acc[c][reg]);
        }
    }
}

// ---------------- aggregate layer 1: ELL, 4 slices x 128 feats, ushort2 gathers ------
// slice-0 blocks also persist the per-edge weights (wts) for reuse by agg2.
__global__ __launch_bounds__(64) void k_agg1(const ushort* __restrict__ h1b,
                                             const int* __restrict__ gdeg,
                                             const int* __restrict__ ell,
                                             const float* __restrict__ b,
                                             ushort* __restrict__ a1b,
                                             float* __restrict__ wts) {
    __shared__ int   sidx[64];
    __shared__ float swt[64];
    int bid = blockIdx.x;
    int slice = bid & 3;
    int v = bid >> 2;
    int t = threadIdx.x;
    int fb = slice * 128 + t * 2;
    int deg = gdeg[v]; if (deg > MAXDEG) deg = MAXDEG;
    float dv = rsqrtf((float)(deg + 1));
    int s = 0; float wt = 0.f;
    if (t < deg) {
        s = ell[v * MAXDEG + t];
        wt = rsqrtf((float)(gdeg[s] + 1)) * dv;
    }
    sidx[t] = s; swt[t] = wt;
    if (slice == 0) wts[v * MAXDEG + t] = wt;   // persist for agg2 (0 for t>=deg)
    __syncthreads();

    float ax[8], ay[8];
#pragma unroll
    for (int k = 0; k < 8; k++) { ax[k] = 0.f; ay[k] = 0.f; }
    {   // self-loop
        ushort2 u = *(const ushort2*)(h1b + (size_t)v * 512 + fb);
        float dv2 = dv * dv;
        ax[0] = bf2f(u.x) * dv2;
        ay[0] = bf2f(u.y) * dv2;
    }
    int nr = (deg + 7) & ~7;                 // extras have w=0, idx=0 (safe)
    for (int i = 0; i < nr; i += 8) {
        int   sK[8]; float wK[8];
#pragma unroll
        for (int k = 0; k < 8; k++) { sK[k] = sidx[i + k]; wK[k] = swt[i + k]; }
#pragma unroll
        for (int k = 0; k < 8; k++) {
            ushort2 u = *(const ushort2*)(h1b + (size_t)sK[k] * 512 + fb);
            ax[k] += bf2f(u.x) * wK[k];
            ay[k] += bf2f(u.y) * wK[k];
        }
    }
    float tx = ((ax[0] + ax[1]) + (ax[2] + ax[3])) + ((ax[4] + ax[5]) + (ax[6] + ax[7]));
    float ty = ((ay[0] + ay[1]) + (ay[2] + ay[3])) + ((ay[4] + ay[5]) + (ay[6] + ay[7]));
    tx += b[fb];
    ty += b[fb + 1];
    ushort2 o;
    o.x = f2bf(tx > 0.f ? tx : 0.f);
    o.y = f2bf(ty > 0.f ? ty : 0.f);
    *(ushort2*)(a1b + (size_t)v * 512 + fb) = o;
}

// ---------------- aggregate layer 2 + bias + log_softmax (ELL + precomputed wts) ----
// R13 lesson: ell slots >= deg are uninitialized poison — clamp the INDEX before
// any gather uses it; w=0 does not guard the load address.
__global__ __launch_bounds__(64) void k_agg2_lsm(const ushort* __restrict__ h2b,
                                                 const int* __restrict__ gdeg,
                                                 const int* __restrict__ ell,
                                                 const float* __restrict__ wts,
                                                 const float* __restrict__ b,
                                                 float* __restrict__ out) {
    __shared__ int   sidx[64];
    __shared__ float swt[64];
    int v = blockIdx.x;
    int t = threadIdx.x;
    int deg = gdeg[v]; if (deg > MAXDEG) deg = MAXDEG;
    float dv = rsqrtf((float)(deg + 1));
    int   e_ = ell[v * MAXDEG + t];            // coalesced, in-bounds
    float w_ = wts[v * MAXDEG + t];            // coalesced, 0 for t>=deg
    sidx[t] = (t < deg) ? e_ : 0;              // clamp index: poison never dereferenced
    swt[t]  = (t < deg) ? w_ : 0.f;
    __syncthreads();

    float acc[8];
#pragma unroll
    for (int k = 0; k < 8; k++) acc[k] = 0.f;
    acc[0] = bf2f(h2b[(size_t)v * 64 + t]) * (dv * dv);

    int nr = (deg + 7) & ~7;
    for (int i = 0; i < nr; i += 8) {
        int   sK[8]; float wK[8];
#pragma unroll
        for (int k = 0; k < 8; k++) { sK[k] = sidx[i + k]; wK[k] = swt[i + k]; }
#pragma unroll
        for (int k = 0; k < 8; k++)
            acc[k] += bf2f(h2b[(size_t)sK[k] * 64 + t]) * wK[k];
    }
    float h = ((acc[0] + acc[1]) + (acc[2] + acc[3])) +
              ((acc[4] + acc[5]) + (acc[6] + acc[7]));
    h += b[t];
    out[(size_t)v * 64 + t] = h;           // output 0: h
    float m = h;
#pragma unroll
    for (int off = 32; off >= 1; off >>= 1) m = fmaxf(m, __shfl_xor(m, off, 64));
    float e = expf(h - m);
    float ssum = e;
#pragma unroll
    for (int off = 32; off >= 1; off >>= 1) ssum += __shfl_xor(ssum, off, 64);
    out[(size_t)NN * OF + (size_t)v * 64 + t] = h - m - logf(ssum);  // output 1
}

// ---------------- launch ----------------

extern "C" void kernel_launch(void* const* d_in, const int* in_sizes, int n_in,
                              void* d_out, int out_size, void* d_ws, size_t ws_size,
                              hipStream_t stream) {
    const float* x  = (const float*)d_in[0];
    const int*   ei = (const int*)d_in[1];
    const float* W1 = (const float*)d_in[2];
    const float* b1 = (const float*)d_in[3];
    const float* W2 = (const float*)d_in[4];
    const float* b2 = (const float*)d_in[5];
    float* out = (float*)d_out;

    int E = in_sizes[1] / 2;             // 163840
    const int* src = ei;
    const int* dst = ei + E;

    char* w = (char*)d_ws;
    auto carve = [&](size_t bytes) {
        char* p = w;
        w += (bytes + 255) & ~size_t(255);
        return p;
    };
    ushort* Xb     = (ushort*)carve((size_t)NN * 512 * 2);
    ushort* h1b    = (ushort*)carve((size_t)NN * 512 * 2);
    ushort* a1b    = (ushort*)carve((size_t)NN * 512 * 2);
    ushort* h2b    = (ushort*)carve((size_t)NN * 64 * 2);
    ushort* W1Tb   = (ushort*)carve((size_t)512 * 512 * 2);
    ushort* W2Tb   = (ushort*)carve((size_t)64 * 512 * 2);
    int*   gdeg    = (int*)carve((size_t)NN * 4);
    int*   ell     = (int*)carve((size_t)NN * MAXDEG * 4);  // 2.56 MB
    float* wts     = (float*)carve((size_t)NN * MAXDEG * 4); // 2.56 MB
    (void)ws_size;

    // 5 dispatches. R12 lesson: do NOT fuse the latency-bound gather phase into a
    // low-block-count kernel. R6 lesson: no cooperative launch. R17 lesson: no
    // persistent mono-kernel (VGPR cap + barrier drains cost 5x).
    int fillB = (E + 255) / 256;
    k_cvt<<<CCB_Z, 256, 0, stream>>>(x, Xb, W1, W1Tb, W2, W2Tb, gdeg);
    k_gemm_ell<<<GEMM_B + fillB, 256, 0, stream>>>(Xb, W1Tb, h1b, src, dst,
                                                   gdeg, ell, E);
    k_agg1<<<NN * 4, 64, 0, stream>>>(h1b, gdeg, ell, b1, a1b, wts);
    k_gemm64_mfma<<<(NN + 63) / 64, 256, 0, stream>>>(a1b, W2Tb, h2b);
    k_agg2_lsm<<<NN, 64, 0, stream>>>(h2b, gdeg, ell, wts, b2, out);
}